// Round 2
// baseline (317.060 us; speedup 1.0000x reference)
//
#include <hip/hip_runtime.h>
#include <math.h>

// Problem constants (match reference)
#define BB 32
#define NN 64
#define CC 8
#define HH 64
#define PP 16
#define LL 8

// One block per batch b. 16 waves (1024 threads); wave w handles path p=w.
// Lane j handles feature dim j (coalesced 256B gathers), then computes
// h[j] and h[j+64] of the 128-wide hidden layer (W1 column reads coalesced).
// Wave 0 lanes 0..15 finish with masked softmax / log-softmax / entropy.
__global__ __launch_bounds__(1024) void path_selector_kernel(
    const float* __restrict__ ef,            // (B,N,N,C,H)
    const float* __restrict__ ge,            // (B,H)
    const int*   __restrict__ sc,            // (B,)
    const int*   __restrict__ paths,         // (B,P,L)
    const int*   __restrict__ plen,          // (B,P)
    const int*   __restrict__ pmask,         // (B,P) bool widened to int32 by harness
    const float* __restrict__ W1,            // (2H,128) = (128,128) row-major
    const float* __restrict__ b1,            // (128,)
    const float* __restrict__ W2,            // (128,)
    const float* __restrict__ b2,            // (1,)
    float* __restrict__ out)                 // action_probs(512) | log_probs(512) | entropy(32)
{
    __shared__ float s_g[HH];        // graph embedding for this b
    __shared__ float s_pf[PP][HH];   // mean-pooled path features
    __shared__ float s_score[PP];

    const int b    = blockIdx.x;
    const int tid  = threadIdx.x;
    const int wave = tid >> 6;
    const int lane = tid & 63;
    const int p    = wave;

    const int c = sc[b];

    if (tid < HH) s_g[tid] = ge[b * HH + tid];

    // ---- path feature gather + mean pool ----
    {
        const int* pp = paths + (b * PP + p) * LL;
        int cnt = plen[b * PP + p] - 1;
        cnt = (cnt < 1) ? 1 : (cnt > LL - 1 ? LL - 1 : cnt);
        // preload path nodes (wave-uniform values)
        int node[LL];
        #pragma unroll
        for (int l = 0; l < LL; ++l) node[l] = pp[l];
        float s = 0.0f;
        for (int e = 0; e < cnt; ++e) {
            int u = node[e];
            int v = node[e + 1];
            int idx = (((b * NN + u) * NN + v) * CC + c) * HH + lane; // < 2^26, fits int
            s += ef[idx];
        }
        s_pf[p][lane] = s / (float)cnt;
    }
    __syncthreads();

    // ---- MLP: h = relu(inp @ W1 + b1); score = h @ W2 + b2 ----
    {
        float h1 = b1[lane];
        float h2 = b1[64 + lane];
        const float* pf = s_pf[p];
        #pragma unroll 8
        for (int k = 0; k < 64; ++k) {          // path_feat half of inp
            float a = pf[k];                    // LDS broadcast (same addr all lanes)
            h1 += a * W1[k * 128 + lane];       // coalesced column read
            h2 += a * W1[k * 128 + 64 + lane];
        }
        #pragma unroll 8
        for (int k = 0; k < 64; ++k) {          // graph-embedding half of inp
            float a = s_g[k];
            h1 += a * W1[(64 + k) * 128 + lane];
            h2 += a * W1[(64 + k) * 128 + 64 + lane];
        }
        h1 = fmaxf(h1, 0.0f);
        h2 = fmaxf(h2, 0.0f);
        float cs = h1 * W2[lane] + h2 * W2[64 + lane];
        // 64-lane reduce
        #pragma unroll
        for (int off = 32; off >= 1; off >>= 1)
            cs += __shfl_down(cs, off, 64);
        if (lane == 0) s_score[p] = cs + b2[0];
    }
    __syncthreads();

    // ---- masked softmax / log-softmax / entropy (wave 0, lanes 0..15) ----
    if (wave == 0 && lane < PP) {
        const bool m = pmask[b * PP + lane] != 0;
        const float s = m ? s_score[lane] : -INFINITY;

        float mx = s;
        #pragma unroll
        for (int off = 8; off >= 1; off >>= 1)
            mx = fmaxf(mx, __shfl_xor(mx, off, 64));   // partners stay in lanes 0..15

        const float e = m ? expf(s - mx) : 0.0f;
        float se = e;
        #pragma unroll
        for (int off = 8; off >= 1; off >>= 1)
            se += __shfl_xor(se, off, 64);

        const float prob = e / se;
        const float lse  = logf(se);
        const float lp   = (s - mx) - lse;             // -inf where masked (matches ref)
        const float lps  = m ? lp : 0.0f;

        float ent = -prob * lps;
        #pragma unroll
        for (int off = 8; off >= 1; off >>= 1)
            ent += __shfl_xor(ent, off, 64);

        out[b * PP + lane]            = prob;          // action_probs
        out[BB * PP + b * PP + lane]  = lp;            // log_probs
        if (lane == 0) out[2 * BB * PP + b] = ent;     // entropy
    }
}

extern "C" void kernel_launch(void* const* d_in, const int* in_sizes, int n_in,
                              void* d_out, int out_size, void* d_ws, size_t ws_size,
                              hipStream_t stream) {
    const float* ef    = (const float*)d_in[0];
    const float* ge    = (const float*)d_in[1];
    const int*   sc    = (const int*)d_in[2];
    const int*   paths = (const int*)d_in[3];
    const int*   plen  = (const int*)d_in[4];
    const int*   pmask = (const int*)d_in[5];
    const float* W1    = (const float*)d_in[6];
    const float* b1    = (const float*)d_in[7];
    const float* W2    = (const float*)d_in[8];
    const float* b2    = (const float*)d_in[9];
    float*       out   = (float*)d_out;

    path_selector_kernel<<<BB, PP * 64, 0, stream>>>(
        ef, ge, sc, paths, plen, pmask, W1, b1, W2, b2, out);
}

// Round 3
// 314.766 us; speedup vs baseline: 1.0073x; 1.0073x over previous
//
#include <hip/hip_runtime.h>
#include <math.h>

// Problem constants (match reference)
#define BB 32
#define NN 64
#define CC 8
#define HH 64
#define PP 16
#define LL 8

// K1: one wave per (b,p) path. 512 waves = 128 blocks x 256 threads.
// Lane j owns feature dim j. Gather+mean-pool in registers, broadcast
// inp[k] via shuffle (no LDS, no barriers), 128-wide MLP, shuffle-reduce
// the W2 dot, lane 0 writes score[b*P+p] to workspace.
__global__ __launch_bounds__(256) void score_kernel(
    const float* __restrict__ ef,            // (B,N,N,C,H)
    const float* __restrict__ ge,            // (B,H)
    const int*   __restrict__ sc,            // (B,)
    const int*   __restrict__ paths,         // (B,P,L)
    const int*   __restrict__ plen,          // (B,P)
    const float* __restrict__ W1,            // (128,128) row-major
    const float* __restrict__ b1,            // (128,)
    const float* __restrict__ W2,            // (128,)
    const float* __restrict__ b2,            // (1,)
    float* __restrict__ scores)              // (B*P,) in d_ws
{
    const int gw   = (blockIdx.x * blockDim.x + threadIdx.x) >> 6;
    const int lane = threadIdx.x & 63;
    const int b    = gw >> 4;
    const int p    = gw & 15;

    const int c = sc[b];

    // ---- gather + mean pool (register-resident, lane = feature dim) ----
    const int* pp = paths + (b * PP + p) * LL;
    int cnt = plen[b * PP + p] - 1;
    cnt = (cnt < 1) ? 1 : (cnt > LL - 1 ? LL - 1 : cnt);
    int node[LL];
    #pragma unroll
    for (int l = 0; l < LL; ++l) node[l] = pp[l];   // wave-uniform
    float s = 0.0f;
    for (int e = 0; e < cnt; ++e) {
        int u = node[e];
        int v = node[e + 1];
        int idx = (((b * NN + u) * NN + v) * CC + c) * HH + lane; // < 2^26
        s += ef[idx];
    }
    const float pf = s / (float)cnt;          // path_feat[lane]
    const float gv = ge[b * HH + lane];       // graph_embedding[lane]

    // ---- MLP: h = relu(inp @ W1 + b1); score = h @ W2 + b2 ----
    float h1 = b1[lane];
    float h2 = b1[64 + lane];
    #pragma unroll 8
    for (int k = 0; k < 64; ++k) {
        float a = __shfl(pf, k, 64);          // broadcast inp[k]
        h1 += a * W1[k * 128 + lane];         // coalesced column read
        h2 += a * W1[k * 128 + 64 + lane];
    }
    #pragma unroll 8
    for (int k = 0; k < 64; ++k) {
        float a = __shfl(gv, k, 64);          // broadcast inp[64+k]
        h1 += a * W1[(64 + k) * 128 + lane];
        h2 += a * W1[(64 + k) * 128 + 64 + lane];
    }
    h1 = fmaxf(h1, 0.0f);
    h2 = fmaxf(h2, 0.0f);
    float cs = h1 * W2[lane] + h2 * W2[64 + lane];
    #pragma unroll
    for (int off = 32; off >= 1; off >>= 1)
        cs += __shfl_down(cs, off, 64);
    if (lane == 0) scores[b * PP + p] = cs + b2[0];
}

// K2: masked softmax / log-softmax / entropy. One block of 64 threads per
// batch; lanes 0..15 active, shfl_xor reductions over the 16 paths.
__global__ __launch_bounds__(64) void softmax_kernel(
    const float* __restrict__ scores,        // (B*P,) from d_ws
    const int*   __restrict__ pmask,         // (B,P) bool widened to int32
    float* __restrict__ out)                 // probs(512) | log_probs(512) | ent(32)
{
    const int b    = blockIdx.x;
    const int lane = threadIdx.x & 63;
    if (lane >= PP) return;

    const bool m = pmask[b * PP + lane] != 0;
    const float s = m ? scores[b * PP + lane] : -INFINITY;

    float mx = s;
    #pragma unroll
    for (int off = 8; off >= 1; off >>= 1)
        mx = fmaxf(mx, __shfl_xor(mx, off, 64));   // partners stay in 0..15

    const float e = m ? expf(s - mx) : 0.0f;
    float se = e;
    #pragma unroll
    for (int off = 8; off >= 1; off >>= 1)
        se += __shfl_xor(se, off, 64);

    const float prob = e / se;
    const float lse  = logf(se);
    const float lp   = (s - mx) - lse;             // -inf where masked (matches ref)
    const float lps  = m ? lp : 0.0f;

    float ent = -prob * lps;
    #pragma unroll
    for (int off = 8; off >= 1; off >>= 1)
        ent += __shfl_xor(ent, off, 64);

    out[b * PP + lane]           = prob;           // action_probs
    out[BB * PP + b * PP + lane] = lp;             // log_probs
    if (lane == 0) out[2 * BB * PP + b] = ent;     // entropy
}

extern "C" void kernel_launch(void* const* d_in, const int* in_sizes, int n_in,
                              void* d_out, int out_size, void* d_ws, size_t ws_size,
                              hipStream_t stream) {
    const float* ef    = (const float*)d_in[0];
    const float* ge    = (const float*)d_in[1];
    const int*   sc    = (const int*)d_in[2];
    const int*   paths = (const int*)d_in[3];
    const int*   plen  = (const int*)d_in[4];
    const int*   pmask = (const int*)d_in[5];
    const float* W1    = (const float*)d_in[6];
    const float* b1    = (const float*)d_in[7];
    const float* W2    = (const float*)d_in[8];
    const float* b2    = (const float*)d_in[9];
    float*       out   = (float*)d_out;
    float*       scores = (float*)d_ws;            // 512 floats of scratch

    // 512 waves (one per path) spread over 128 blocks
    score_kernel<<<(BB * PP) / 4, 256, 0, stream>>>(
        ef, ge, sc, paths, plen, W1, b1, W2, b2, scores);
    softmax_kernel<<<BB, 64, 0, stream>>>(scores, pmask, out);
}